// Round 7
// baseline (725.168 us; speedup 1.0000x reference)
//
#include <hip/hip_runtime.h>

#define K 7
#define PAD 3
#define TH 8
#define LH (TH + 2 * PAD)   // 14 staged rows
#define LSTRIDE 520         // floats per LDS row (16B-aligned rows)
#define NREP 4              // instrumentation: repeat identical work to surface counters
// LDS col layout per row: [0..3]=zero pad, [4..515]=sal, [516..519]=zero pad

typedef float f32x4 __attribute__((ext_vector_type(4)));

constexpr int H_ = 512, W_ = 512, HW_ = H_ * W_, K2 = K * K;

__global__ __launch_bounds__(1024) void adaptive_aggregation_kernel(
    const float* __restrict__ thick,
    const float* __restrict__ thin,
    const float* __restrict__ coeff,
    float* __restrict__ out)
{
    __shared__ float sal[LH][LSTRIDE];   // 29.1 KB

    const int b  = blockIdx.y;
    const int h0 = blockIdx.x * TH;
    const int tx = threadIdx.x;          // 0..127
    const int ty = threadIdx.y;          // 0..7
    const int tid = ty * 128 + tx;
    const size_t base1 = (size_t)b * HW_;

    #pragma unroll 1
    for (int rep = 0; rep < NREP; ++rep) {

        // ---- zero the 8 horizontal-halo floats of each row ----
        if (tid < LH * 2) {
            const int r = tid >> 1;
            const int c = (tid & 1) ? (LSTRIDE - 4) : 0;
            *reinterpret_cast<f32x4*>(&sal[r][c]) = (f32x4)0.f;
        }

        // ---- stage sal = max(thick,thin): coalesced float4, 2 passes ----
        #pragma unroll
        for (int pass = 0; pass < 2; ++pass) {
            const int r = pass * 8 + ty;
            if (r < LH) {
                const int gh = h0 - PAD + r;
                f32x4 v = (f32x4)0.f;
                if (gh >= 0 && gh < H_) {
                    const size_t off = base1 + (size_t)gh * W_ + tx * 4;
                    const f32x4 a = *reinterpret_cast<const f32x4*>(thick + off);
                    const f32x4 t = *reinterpret_cast<const f32x4*>(thin + off);
                    v.x = fmaxf(a.x, t.x);
                    v.y = fmaxf(a.y, t.y);
                    v.z = fmaxf(a.z, t.z);
                    v.w = fmaxf(a.w, t.w);
                }
                *reinterpret_cast<f32x4*>(&sal[r][4 + tx * 4]) = v;
            }
        }
        __syncthreads();

        // ---- 4 consecutive output pixels at (h0+ty, tx*4 ..+3) ----
        const int h = h0 + ty;
        const int w4 = tx * 4;
        const float* cptr = coeff + (size_t)b * (K2 * HW_) + h * W_ + w4;

        float acc0 = 0.f, acc1 = 0.f, acc2 = 0.f, acc3 = 0.f;

        #pragma unroll
        for (int i = 0; i < K; ++i) {
            f32x4 c4[K];
            #pragma unroll
            for (int j = 0; j < K; ++j)
                c4[j] = __builtin_nontemporal_load(
                    reinterpret_cast<const f32x4*>(cptr + (i * K + j) * HW_));

            float row[K + 3];
            #pragma unroll
            for (int c = 0; c < K + 3; ++c)
                row[c] = sal[ty + i][w4 + 1 + c];

            #pragma unroll
            for (int j = 0; j < K; ++j) {
                acc0 = fmaf(row[j + 0], c4[j].x, acc0);
                acc1 = fmaf(row[j + 1], c4[j].y, acc1);
                acc2 = fmaf(row[j + 2], c4[j].z, acc2);
                acc3 = fmaf(row[j + 3], c4[j].w, acc3);
            }
        }

        f32x4 o;
        o.x = acc0; o.y = acc1; o.z = acc2; o.w = acc3;
        __builtin_nontemporal_store(
            o, reinterpret_cast<f32x4*>(out + base1 + (size_t)h * W_ + w4));

        __syncthreads();   // LDS reuse across reps
    }
}

extern "C" void kernel_launch(void* const* d_in, const int* in_sizes, int n_in,
                              void* d_out, int out_size, void* d_ws, size_t ws_size,
                              hipStream_t stream) {
    const float* thick = (const float*)d_in[0];
    const float* thin  = (const float*)d_in[1];
    const float* coeff = (const float*)d_in[2];
    float* out = (float*)d_out;

    const int B = in_sizes[0] / HW_;       // 8

    dim3 grid(H_ / TH, B);                 // (64, 8) = 512 blocks
    dim3 block(128, 8);                    // 1024 threads = 16 waves

    hipLaunchKernelGGL(adaptive_aggregation_kernel, grid, block, 0, stream,
                       thick, thin, coeff, out);
}

// Round 9
// 513.641 us; speedup vs baseline: 1.4118x; 1.4118x over previous
//
#include <hip/hip_runtime.h>

#define K 7
#define PAD 3
#define TH 8
#define LH (TH + 2 * PAD)   // 14 staged rows
#define LSTRIDE 520         // floats per LDS row (16B-aligned rows)
// LDS col layout per row: [0..3]=zero pad, [4..515]=sal, [516..519]=zero pad
// (horizontal halo at full-width stripes is always out-of-bounds -> zero)

typedef float f32x4 __attribute__((ext_vector_type(4)));

constexpr int H_ = 512, W_ = 512, HW_ = H_ * W_, K2 = K * K;

// __launch_bounds__(1024, 4): 4 waves/EU = exactly 1 block/CU resident,
// which lifts the VGPR cap to 128 (r7 showed 64-VGPR cap -> 85MB/rep spills)
__global__ __launch_bounds__(1024, 4) void adaptive_aggregation_kernel(
    const float* __restrict__ thick,
    const float* __restrict__ thin,
    const float* __restrict__ coeff,
    float* __restrict__ out)
{
    __shared__ float sal[LH][LSTRIDE];   // 29.1 KB

    const int b  = blockIdx.y;
    const int h0 = blockIdx.x * TH;
    const int tx = threadIdx.x;          // 0..127
    const int ty = threadIdx.y;          // 0..7
    const int tid = ty * 128 + tx;
    const size_t base1 = (size_t)b * HW_;

    // ---- zero the 8 horizontal-halo floats of each row (f32x4 writes) ----
    if (tid < LH * 2) {
        const int r = tid >> 1;
        const int c = (tid & 1) ? (LSTRIDE - 4) : 0;
        *reinterpret_cast<f32x4*>(&sal[r][c]) = (f32x4)0.f;
    }

    // ---- stage sal = max(thick,thin): fully coalesced float4, 2 passes ----
    #pragma unroll
    for (int pass = 0; pass < 2; ++pass) {
        const int r = pass * 8 + ty;
        if (r < LH) {
            const int gh = h0 - PAD + r;
            f32x4 v = (f32x4)0.f;
            if (gh >= 0 && gh < H_) {
                const size_t off = base1 + (size_t)gh * W_ + tx * 4;
                const f32x4 a = *reinterpret_cast<const f32x4*>(thick + off);
                const f32x4 t = *reinterpret_cast<const f32x4*>(thin + off);
                v.x = fmaxf(a.x, t.x);
                v.y = fmaxf(a.y, t.y);
                v.z = fmaxf(a.z, t.z);
                v.w = fmaxf(a.w, t.w);
            }
            *reinterpret_cast<f32x4*>(&sal[r][4 + tx * 4]) = v;  // 16B aligned
        }
    }
    __syncthreads();

    // ---- each thread: 4 consecutive output pixels at (h0+ty, tx*4 ..+3) ----
    const int h = h0 + ty;
    const int w4 = tx * 4;
    const float* cptr = coeff + (size_t)b * (K2 * HW_) + h * W_ + w4;

    float acc0 = 0.f, acc1 = 0.f, acc2 = 0.f, acc3 = 0.f;

    #pragma unroll
    for (int i = 0; i < K; ++i) {
        // aligned window: 4x ds_read_b128 covering floats [w4 .. w4+15];
        // needed window is [w4+1 .. w4+13] -> static element select, no conflicts
        const float* lrow = &sal[ty + i][w4];   // 16B aligned (w4 = tx*4)
        const f32x4 r0 = *reinterpret_cast<const f32x4*>(lrow + 0);
        const f32x4 r1 = *reinterpret_cast<const f32x4*>(lrow + 4);
        const f32x4 r2 = *reinterpret_cast<const f32x4*>(lrow + 8);
        const f32x4 r3 = *reinterpret_cast<const f32x4*>(lrow + 12);
        const float row[16] = { r0.x, r0.y, r0.z, r0.w,
                                r1.x, r1.y, r1.z, r1.w,
                                r2.x, r2.y, r2.z, r2.w,
                                r3.x, r3.y, r3.z, r3.w };

        #pragma unroll
        for (int j = 0; j < K; ++j) {
            // direct-use nontemporal load: one f32x4 in flight per FMA group,
            // no c4[7] array -> no spill pressure
            const f32x4 c4 = __builtin_nontemporal_load(
                reinterpret_cast<const f32x4*>(cptr + (i * K + j) * HW_));
            acc0 = fmaf(row[j + 1], c4.x, acc0);
            acc1 = fmaf(row[j + 2], c4.y, acc1);
            acc2 = fmaf(row[j + 3], c4.z, acc2);
            acc3 = fmaf(row[j + 4], c4.w, acc3);
        }
    }

    f32x4 o;
    o.x = acc0; o.y = acc1; o.z = acc2; o.w = acc3;
    __builtin_nontemporal_store(
        o, reinterpret_cast<f32x4*>(out + base1 + (size_t)h * W_ + w4));
}

extern "C" void kernel_launch(void* const* d_in, const int* in_sizes, int n_in,
                              void* d_out, int out_size, void* d_ws, size_t ws_size,
                              hipStream_t stream) {
    const float* thick = (const float*)d_in[0];
    const float* thin  = (const float*)d_in[1];
    const float* coeff = (const float*)d_in[2];
    float* out = (float*)d_out;

    const int B = in_sizes[0] / HW_;       // 8

    dim3 grid(H_ / TH, B);                 // (64, 8) = 512 blocks
    dim3 block(128, 8);                    // 1024 threads = 16 waves

    hipLaunchKernelGGL(adaptive_aggregation_kernel, grid, block, 0, stream,
                       thick, thin, coeff, out);
}